// Round 17
// baseline (315.135 us; speedup 1.0000x reference)
//
#include <hip/hip_runtime.h>
#include <hip/hip_bf16.h>
#include <stdint.h>

#define NN 32768
#define KK 1024
#define DD 256
#define CHUNK 128
#define NTHR 512

// ws float region: [0,1024) np2 | [1024,2048) colsum_y | [2048,3072) colsumS | [3072] sumlz
// ws byte offsets:
#define PB_OFF   16384
#define XB_OFF   (PB_OFF + 524288)       // bf16 latents, 16MB
#define ZROW_OFF (XB_OFF + 16777216)     // f32[32768]
#define MM_OFF   (ZROW_OFF + 131072)     // u64[32768] packed (max,argmax)
#define LZB_OFF  (MM_OFF + 262144)       // f32[32768]
#define MIB_OFF  (LZB_OFF + 131072)      // i32[32768]
#define WS_NEED  (MIB_OFF + 131072)      // ~17.2 MB
#define WS_PRE   (PB_OFF + 524288)

// fallback (round-9 structure) LDS
#define BMF 16
#define LXS 0
#define LSS 8192
#define LRM (LSS + 32768)
#define LRI (LRM + 64)
#define FLPS 41216
#define LTOT_PRE  41216
#define LTOT_NPRE (41216 + 65536)

typedef __attribute__((ext_vector_type(8))) short bf16x8;
typedef __attribute__((ext_vector_type(4))) float f32x4;

__device__ __forceinline__ uint32_t pkbf2(float a, float b) {  // RNE f32->bf16 pack
    uint32_t ua = __builtin_bit_cast(uint32_t, a);
    uint32_t ub = __builtin_bit_cast(uint32_t, b);
    ua = (ua + 0x7fffu + ((ua >> 16) & 1u)) >> 16;
    ub = (ub + 0x7fffu + ((ub >> 16) & 1u)) >> 16;
    return ua | (ub << 16);
}
__device__ __forceinline__ float ubf(uint32_t h) {
    return __builtin_bit_cast(float, h << 16);
}
__device__ __forceinline__ unsigned long long packmi(float m, int mi) {
    uint32_t u = __builtin_bit_cast(uint32_t, m);
    u = (u & 0x80000000u) ? ~u : (u | 0x80000000u);   // monotonic float->uint
    return ((unsigned long long)u << 32) | (unsigned long long)(0xFFFFFFFFu - (uint32_t)mi);
}

__global__ void vq_init(const float* __restrict__ protos, float* __restrict__ ws) {
    int k = blockIdx.x * 256 + threadIdx.x;   // grid 4 x 256
    const float4* p4 = reinterpret_cast<const float4*>(protos + (size_t)k * DD);
    float s = 0.f;
#pragma unroll 8
    for (int j = 0; j < DD / 4; ++j) {
        float4 v = p4[j];
        s = fmaf(v.x, v.x, s); s = fmaf(v.y, v.y, s);
        s = fmaf(v.z, v.z, s); s = fmaf(v.w, v.w, s);
    }
    ws[k] = s;
    ws[KK + k] = 0.f;       // colsum_y
    ws[2 * KK + k] = 0.f;   // colsumS
    if (k == 0) ws[3 * KK] = 0.f;   // sumlz
}

__global__ void vq_zero(float* __restrict__ ws) {
    int i = blockIdx.x * NTHR + threadIdx.x;   // grid 192 -> 98304 = (zrow+mm)/4
    reinterpret_cast<uint32_t*>((char*)ws + ZROW_OFF)[i] = 0u;
}

__global__ void vq_cvt(const float* __restrict__ src, uint32_t* __restrict__ dst) {
    int idx = blockIdx.x * 256 + threadIdx.x;  // 8 floats each
    const float4* s = reinterpret_cast<const float4*>(src + (size_t)idx * 8);
    float4 a = s[0], b = s[1];
    uint4 v;
    v.x = pkbf2(a.x, a.y); v.y = pkbf2(a.z, a.w);
    v.z = pkbf2(b.x, b.y); v.w = pkbf2(b.z, b.w);
    reinterpret_cast<uint4*>(dst)[idx] = v;
}

// ==== passA: codebook-resident, barrier-free, zero-LDS main loop ====
// r16 lesson: launch_bounds only CAPS registers; the allocator rematerialized
// the 8 loop-invariant A-frags (VGPR=32, 8 L2-load->MFMA dependent chain).
// Fix: opaque asm pin forces the frags to stay register-resident.
// PASS 1: row z/max/argmax (atomics) + column sum of S (colsumS).
// PASS 2: column sum of exp(S - lz) (colsum_y), using lzb from vq_rowstat.
template<int PASS>
__global__ __launch_bounds__(NTHR, 2) void vq_passA(const float* __restrict__ gumbel,
                                                    float* __restrict__ ws) {
    const int t = threadIdx.x;
    const int lane = t & 63;
    const int w = t >> 6;
    const int l15 = lane & 15;
    const int l4 = lane >> 4;
    const int c = blockIdx.x & 7;          // chunk
    const int rg = blockIdx.x >> 3;        // row-group: 512 rows
    const float* np2 = ws;
    float* colsum_y = ws + KK;
    float* colsumS = ws + 2 * KK;
    const uint4* pb = reinterpret_cast<const uint4*>((char*)ws + PB_OFF);
    const uint4* xb = reinterpret_cast<const uint4*>((char*)ws + XB_OFF);
    float* zrow = reinterpret_cast<float*>((char*)ws + ZROW_OFF);
    unsigned long long* mm = reinterpret_cast<unsigned long long*>((char*)ws + MM_OFF);
    const float* lzb = reinterpret_cast<const float*>((char*)ws + LZB_OFF);

    // loop-invariant A-fragments (this wave's 16 protos), 32 VGPR
    const uint4* afp = pb + (size_t)(c * CHUNK + w * 16 + l15) * 32;
    bf16x8 af0 = __builtin_bit_cast(bf16x8, afp[0 * 4 + l4]);
    bf16x8 af1 = __builtin_bit_cast(bf16x8, afp[1 * 4 + l4]);
    bf16x8 af2 = __builtin_bit_cast(bf16x8, afp[2 * 4 + l4]);
    bf16x8 af3 = __builtin_bit_cast(bf16x8, afp[3 * 4 + l4]);
    bf16x8 af4 = __builtin_bit_cast(bf16x8, afp[4 * 4 + l4]);
    bf16x8 af5 = __builtin_bit_cast(bf16x8, afp[5 * 4 + l4]);
    bf16x8 af6 = __builtin_bit_cast(bf16x8, afp[6 * 4 + l4]);
    bf16x8 af7 = __builtin_bit_cast(bf16x8, afp[7 * 4 + l4]);
    // pin in registers: opaque to the optimizer -> cannot rematerialize
    asm volatile("" : "+v"(af0), "+v"(af1), "+v"(af2), "+v"(af3),
                      "+v"(af4), "+v"(af5), "+v"(af6), "+v"(af7));

    const int pg0 = c * CHUNK + w * 16 + l4 * 4;   // 4 output columns
    const float4 q4 = *reinterpret_cast<const float4*>(np2 + pg0);
    float cA0 = 0.f, cA1 = 0.f, cA2 = 0.f, cA3 = 0.f;
    const int nbase = rg * 512;

    for (int rt = 0; rt < 32; ++rt) {
        const int row = nbase + rt * 16 + l15;
        const uint4* xr = xb + (size_t)row * 32;
        float4 g4 = *reinterpret_cast<const float4*>(gumbel + (size_t)row * KK + pg0);

        f32x4 acc = {0.f, 0.f, 0.f, 0.f};
#define AKS(k, afk) { bf16x8 bf = __builtin_bit_cast(bf16x8, xr[(k) * 4 + l4]); \
        acc = __builtin_amdgcn_mfma_f32_16x16x32_bf16(afk, bf, acc, 0, 0, 0); }
        AKS(0, af0) AKS(1, af1) AKS(2, af2) AKS(3, af3)
        AKS(4, af4) AKS(5, af5) AKS(6, af6) AKS(7, af7)
#undef AKS
        float s0 = fmaf(2.f, acc.x, -q4.x) + g4.x;
        float s1 = fmaf(2.f, acc.y, -q4.y) + g4.y;
        float s2 = fmaf(2.f, acc.z, -q4.z) + g4.z;
        float s3 = fmaf(2.f, acc.w, -q4.w) + g4.w;

        if (PASS == 1) {
            cA0 += s0; cA1 += s1; cA2 += s2; cA3 += s3;
            float zp = __expf(s0) + __expf(s1) + __expf(s2) + __expf(s3);
            float mv = s0; int mi = pg0;
            if (s1 > mv) { mv = s1; mi = pg0 + 1; }
            if (s2 > mv) { mv = s2; mi = pg0 + 2; }
            if (s3 > mv) { mv = s3; mi = pg0 + 3; }
#pragma unroll
            for (int off = 16; off <= 32; off <<= 1) {
                float om = __shfl_xor(mv, off); int oi = __shfl_xor(mi, off);
                if (om > mv || (om == mv && oi < mi)) { mv = om; mi = oi; }
                zp += __shfl_xor(zp, off);
            }
            if (l4 == 0) {
                atomicAdd(&zrow[row], zp);
                atomicMax(&mm[row], packmi(mv, mi));
            }
        } else {
            float lz = lzb[row];
            cA0 += __expf(s0 - lz);
            cA1 += __expf(s1 - lz);
            cA2 += __expf(s2 - lz);
            cA3 += __expf(s3 - lz);
        }
    }
    // reduce column accumulators across l15 (lane bits 0-3): same columns, different rows
#pragma unroll
    for (int off = 1; off <= 8; off <<= 1) {
        cA0 += __shfl_xor(cA0, off); cA1 += __shfl_xor(cA1, off);
        cA2 += __shfl_xor(cA2, off); cA3 += __shfl_xor(cA3, off);
    }
    if (l15 == 0) {
        float* dst = (PASS == 1) ? colsumS : colsum_y;
        atomicAdd(&dst[pg0],     cA0);
        atomicAdd(&dst[pg0 + 1], cA1);
        atomicAdd(&dst[pg0 + 2], cA2);
        atomicAdd(&dst[pg0 + 3], cA3);
    }
}

__global__ __launch_bounds__(NTHR) void vq_rowstat(float* __restrict__ ws) {
    __shared__ float part[8];
    int n = blockIdx.x * NTHR + threadIdx.x;   // grid 64
    const float* zrow = reinterpret_cast<const float*>((char*)ws + ZROW_OFF);
    const unsigned long long* mm =
        reinterpret_cast<const unsigned long long*>((char*)ws + MM_OFF);
    float* lzb = reinterpret_cast<float*>((char*)ws + LZB_OFF);
    int* mib = reinterpret_cast<int*>((char*)ws + MIB_OFF);

    float lz = __logf(zrow[n]);
    lzb[n] = lz;
    mib[n] = (int)(0xFFFFFFFFu - (uint32_t)(mm[n] & 0xFFFFFFFFull));
    float a = lz;
#pragma unroll
    for (int off = 1; off <= 32; off <<= 1) a += __shfl_xor(a, off);
    if ((threadIdx.x & 63) == 0) part[threadIdx.x >> 6] = a;
    __syncthreads();
    if (threadIdx.x == 0) {
        float s = 0.f;
#pragma unroll
        for (int j = 0; j < 8; ++j) s += part[j];
        atomicAdd(&ws[3 * KK], s);
    }
}

__global__ __launch_bounds__(NTHR) void vq_gather(const float* __restrict__ protos,
                                                  const float* __restrict__ ws,
                                                  float* __restrict__ out) {
    const int* mib = reinterpret_cast<const int*>((char*)ws + MIB_OFF);
    int n0 = blockIdx.x * 16;                 // grid 2048
    int row = threadIdx.x >> 5, v = threadIdx.x & 31;
    int idx = mib[n0 + row];
    const float4* src = reinterpret_cast<const float4*>(protos + (size_t)idx * DD + v * 8);
    float4* dst = reinterpret_cast<float4*>(out + (size_t)(n0 + row) * DD + v * 8);
    dst[0] = src[0];
    dst[1] = src[1];
}

__global__ void vq_final(const float* __restrict__ ws,
                         float* __restrict__ out, int out_size) {
    __shared__ float part[4];
    int t = threadIdx.x;  // 1 block x 256
    const float invN = 1.0f / (float)NN;
    const float sumlz = ws[3 * KK];
    float a = 0.f;
    for (int j = 0; j < 4; ++j) {
        int k = t + j * 256;
        float prior = fmaf(ws[KK + k], invN, 1e-6f);
        float Lk = (ws[2 * KK + k] - sumlz) * invN;
        a += prior * (1.001f * __logf(prior) - Lk);
    }
#pragma unroll
    for (int off = 32; off >= 1; off >>= 1) a += __shfl_xor(a, off);
    if ((t & 63) == 0) part[t >> 6] = a;
    __syncthreads();
    if (t == 0) {
        out[out_size - 1] = part[0] + part[1] + part[2] + part[3];
    }
}

// ======= fallback main kernel (round-9 structure, colsum_lp semantics) =======
template<bool PRE>
__global__ __launch_bounds__(NTHR) void vq_mainT(const float* __restrict__ latents,
                                                 const float* __restrict__ protos,
                                                 const float* __restrict__ gumbel,
                                                 float* __restrict__ ws,
                                                 float* __restrict__ out) {
    __shared__ __align__(16) unsigned char sm[PRE ? LTOT_PRE : LTOT_NPRE];
    const int t = threadIdx.x;
    const int lane = t & 63;
    const int w = t >> 6;
    const int n0 = blockIdx.x * BMF;
    const int l15 = lane & 15;
    const int l4 = lane >> 4;
    const float* np2 = ws;
    float* colsum_y = ws + KK;
    float* colsumS = ws + 2 * KK;    // store sum of S; lz handled via sumlz
    const uint4* pb = reinterpret_cast<const uint4*>((char*)ws + PB_OFF);

    {
        int row = t >> 5, g = t & 31;
        const float4* src = reinterpret_cast<const float4*>(
            latents + (size_t)(n0 + row) * DD + g * 8);
        float4 a = src[0], b = src[1];
        uint4 v; v.x = pkbf2(a.x, a.y); v.y = pkbf2(a.z, a.w);
        v.z = pkbf2(b.x, b.y); v.w = pkbf2(b.z, b.w);
        *reinterpret_cast<uint4*>(sm + LXS + row * 512 + ((g ^ (row & 7)) << 4)) = v;
    }
    __syncthreads();

    const int pr = w * 16 + l15;
    const int cwbase = w * 16 + l4 * 4;

    for (int c = 0; c < 8; ++c) {
        if (!PRE) {
            __syncthreads();
#pragma unroll
            for (int i = 0; i < 8; ++i) {
                int G = t + NTHR * i;
                int p = G >> 5, g = G & 31;
                const float4* src = reinterpret_cast<const float4*>(
                    protos + (size_t)(c * 128 + p) * DD + g * 8);
                float4 a = src[0], b = src[1];
                uint4 v; v.x = pkbf2(a.x, a.y); v.y = pkbf2(a.z, a.w);
                v.z = pkbf2(b.x, b.y); v.w = pkbf2(b.z, b.w);
                *reinterpret_cast<uint4*>(sm + FLPS + p * 512 + ((g ^ (p & 7)) << 4)) = v;
            }
            __syncthreads();
        }
        const int pg0 = c * 128 + cwbase;
        float4 q4 = *reinterpret_cast<const float4*>(np2 + pg0);
        float4 g4 = *reinterpret_cast<const float4*>(gumbel + (size_t)(n0 + l15) * KK + pg0);

        f32x4 acc = {0.f, 0.f, 0.f, 0.f};
        if (PRE) {
            const uint4* afp = pb + (size_t)(c * 128 + pr) * 32;
#pragma unroll
            for (int ks = 0; ks < 8; ++ks) {
                int gi = ks * 4 + l4;
                bf16x8 af = __builtin_bit_cast(bf16x8, afp[gi]);
                bf16x8 b0 = *reinterpret_cast<bf16x8*>(
                    sm + LXS + l15 * 512 + ((gi ^ (l15 & 7)) << 4));
                acc = __builtin_amdgcn_mfma_f32_16x16x32_bf16(af, b0, acc, 0, 0, 0);
            }
        } else {
#pragma unroll
            for (int ks = 0; ks < 8; ++ks) {
                int gi = ks * 4 + l4;
                bf16x8 af = *reinterpret_cast<bf16x8*>(
                    sm + FLPS + pr * 512 + ((gi ^ (pr & 7)) << 4));
                bf16x8 b0 = *reinterpret_cast<bf16x8*>(
                    sm + LXS + l15 * 512 + ((gi ^ (l15 & 7)) << 4));
                acc = __builtin_amdgcn_mfma_f32_16x16x32_bf16(af, b0, acc, 0, 0, 0);
            }
        }
        {
            const int Gs = pg0 >> 2;
            uint2 pk;
            pk.x = pkbf2(fmaf(2.f, acc.x, -q4.x) + g4.x, fmaf(2.f, acc.y, -q4.y) + g4.y);
            pk.y = pkbf2(fmaf(2.f, acc.z, -q4.z) + g4.z, fmaf(2.f, acc.w, -q4.w) + g4.w);
            *reinterpret_cast<uint2*>(sm + LSS + l15 * 2048 + ((Gs ^ ((l15 & 7) << 1)) << 3)) = pk;
        }
    }
    __syncthreads();

    {
        int row = t >> 5, v = t & 31;
        int sw = (row & 7) << 1;
        uint2 d[8];
#pragma unroll
        for (int j = 0; j < 8; ++j) {
            int G = v + 32 * j;
            d[j] = *reinterpret_cast<uint2*>(sm + LSS + row * 2048 + ((G ^ sw) << 3));
        }
        float m = -3.4e38f; int mi = 0;
#pragma unroll
        for (int j = 0; j < 8; ++j) {
            int c0 = (v + 32 * j) * 4;
            float f0 = ubf(d[j].x & 0xffffu), f1 = ubf(d[j].x >> 16);
            float f2 = ubf(d[j].y & 0xffffu), f3 = ubf(d[j].y >> 16);
            if (f0 > m) { m = f0; mi = c0; }
            if (f1 > m) { m = f1; mi = c0 + 1; }
            if (f2 > m) { m = f2; mi = c0 + 2; }
            if (f3 > m) { m = f3; mi = c0 + 3; }
        }
#pragma unroll
        for (int off = 1; off < 32; off <<= 1) {
            float om = __shfl_xor(m, off);
            int oi = __shfl_xor(mi, off);
            if (om > m || (om == m && oi < mi)) { m = om; mi = oi; }
        }
        float se = 0.f;
#pragma unroll
        for (int j = 0; j < 8; ++j) {
            se += __expf(ubf(d[j].x & 0xffffu) - m);
            se += __expf(ubf(d[j].x >> 16) - m);
            se += __expf(ubf(d[j].y & 0xffffu) - m);
            se += __expf(ubf(d[j].y >> 16) - m);
        }
#pragma unroll
        for (int off = 1; off < 32; off <<= 1) se += __shfl_xor(se, off);
        if (v == 0) {
            float lz = m + __logf(se);
            *reinterpret_cast<float*>(sm + LRM + row * 4) = lz;
            *reinterpret_cast<int*>(sm + LRI + row * 4) = mi;
            atomicAdd(&ws[3 * KK], lz);    // sumlz
        }
    }
    __syncthreads();

#pragma unroll
    for (int h = 0; h < 2; ++h) {
        int col = t + h * NTHR;
        int G = col >> 2;
        int e2 = (col & 3) << 1;
        float sy = 0.f, ss = 0.f;
#pragma unroll 8
        for (int r = 0; r < BMF; ++r) {
            uint32_t hv = *reinterpret_cast<uint16_t*>(
                sm + LSS + r * 2048 + ((G ^ ((r & 7) << 1)) << 3) + e2);
            float lz = *reinterpret_cast<float*>(sm + LRM + r * 4);
            float sv = ubf(hv);
            ss += sv;
            sy += __expf(sv - lz);
        }
        atomicAdd(&colsum_y[col], sy);
        atomicAdd(&colsumS[col], ss);
    }

    {
        int row = t >> 5, v = t & 31;
        int idx = *reinterpret_cast<int*>(sm + LRI + row * 4);
        const float4* src = reinterpret_cast<const float4*>(protos + (size_t)idx * DD + v * 8);
        float4* dst = reinterpret_cast<float4*>(out + (size_t)(n0 + row) * DD + v * 8);
        dst[0] = src[0];
        dst[1] = src[1];
    }
}

extern "C" void kernel_launch(void* const* d_in, const int* in_sizes, int n_in,
                              void* d_out, int out_size, void* d_ws, size_t ws_size,
                              hipStream_t stream) {
    (void)in_sizes; (void)n_in;
    const float* latents = (const float*)d_in[0];
    const float* protos  = (const float*)d_in[1];
    const float* gumbel  = (const float*)d_in[2];
    float* out           = (float*)d_out;
    float* ws            = (float*)d_ws;

    vq_init<<<dim3(4), dim3(256), 0, stream>>>(protos, ws);
    if (ws_size >= WS_NEED) {
        vq_zero<<<dim3(192), dim3(NTHR), 0, stream>>>(ws);
        vq_cvt<<<dim3(128), dim3(256), 0, stream>>>(
            protos, (uint32_t*)((char*)d_ws + PB_OFF));
        vq_cvt<<<dim3(4096), dim3(256), 0, stream>>>(
            latents, (uint32_t*)((char*)d_ws + XB_OFF));
        vq_passA<1><<<dim3(512), dim3(NTHR), 0, stream>>>(gumbel, ws);
        vq_rowstat<<<dim3(64), dim3(NTHR), 0, stream>>>(ws);
        vq_passA<2><<<dim3(512), dim3(NTHR), 0, stream>>>(gumbel, ws);
        vq_gather<<<dim3(2048), dim3(NTHR), 0, stream>>>(protos, ws, out);
    } else if (ws_size >= WS_PRE) {
        vq_cvt<<<dim3(128), dim3(256), 0, stream>>>(
            protos, (uint32_t*)((char*)d_ws + PB_OFF));
        vq_mainT<true><<<dim3(NN / BMF), dim3(NTHR), 0, stream>>>(
            latents, protos, gumbel, ws, out);
    } else {
        vq_mainT<false><<<dim3(NN / BMF), dim3(NTHR), 0, stream>>>(
            latents, protos, gumbel, ws, out);
    }
    vq_final<<<dim3(1), dim3(256), 0, stream>>>(ws, out, out_size);
}

// Round 18
// 124.023 us; speedup vs baseline: 2.5409x; 2.5409x over previous
//
#include <hip/hip_runtime.h>
#include <hip/hip_bf16.h>
#include <stdint.h>

#define NN 32768
#define KK 1024
#define DD 256
#define BM 16
#define CHUNK 128
#define NCHUNK (KK / CHUNK)   // 8
#define NTHR 512
#define NRB (NN / BM)         // 2048 row-blocks

// ---- kernel A LDS: Xs 8KB | Ps 64KB | scratch ----
#define LXS 0
#define LPS 8192
#define ASC_MAXP 73728   // [16 rows][8 waves] {f32 m, i32 mi} = 1024B
#define ASC_ZP   74752   // [16][8] f32 = 512B
#define ASC_MI   75264   // [16] i32
#define LA_TOT   75328

// ---- round-9 fallback LDS ----
#define LSS 8192
#define LRM (LSS + 32768)
#define LRI (LRM + 64)
#define FLPS 41216
#define LTOT_PRE  41216
#define LTOT_NPRE (41216 + 65536)

// ws layout (bytes):
// [0, 4096)        np2 f32[1024]
// [4096, 8192)     colsum_y f32[1024]
// [8192, 12288)    colsum_lp f32[1024]
// [12288, 536576)  pb: bf16 protos, uint4-granules
// [536576, +64MB)  Sbuf uint2[NRB*8*512]   (full path only)
// [67645440, +128KB) lzbuf f32[NN]
#define PB_OFF   12288
#define SBUF_OFF 536576
#define LZ_OFF   (SBUF_OFF + (size_t)NRB * NCHUNK * 512 * 8)   // 67645440
#define WS_FULL  (LZ_OFF + (size_t)NN * 4)
#define WS_PRE   (PB_OFF + (size_t)KK * DD * 2)

typedef __attribute__((ext_vector_type(8))) short bf16x8;
typedef __attribute__((ext_vector_type(4))) float f32x4;

__device__ __forceinline__ uint32_t pkbf2(float a, float b) {  // RNE f32->bf16 pack
    uint32_t ua = __builtin_bit_cast(uint32_t, a);
    uint32_t ub = __builtin_bit_cast(uint32_t, b);
    ua = (ua + 0x7fffu + ((ua >> 16) & 1u)) >> 16;
    ub = (ub + 0x7fffu + ((ub >> 16) & 1u)) >> 16;
    return ua | (ub << 16);
}
__device__ __forceinline__ float ubf(uint32_t h) {
    return __builtin_bit_cast(float, h << 16);
}

__global__ void vq_init(const float* __restrict__ protos, float* __restrict__ ws) {
    int k = blockIdx.x * 256 + threadIdx.x;   // grid 4 x 256
    const float4* p4 = reinterpret_cast<const float4*>(protos + (size_t)k * DD);
    float s = 0.f;
#pragma unroll 8
    for (int j = 0; j < DD / 4; ++j) {
        float4 v = p4[j];
        s = fmaf(v.x, v.x, s); s = fmaf(v.y, v.y, s);
        s = fmaf(v.z, v.z, s); s = fmaf(v.w, v.w, s);
    }
    ws[k] = s;
    ws[KK + k] = 0.f;
    ws[2 * KK + k] = 0.f;
}

__global__ void vq_cvt(const float* __restrict__ protos, uint32_t* __restrict__ pb) {
    int idx = blockIdx.x * 256 + threadIdx.x;  // 0..32767
    const float4* s = reinterpret_cast<const float4*>(protos + (size_t)idx * 8);
    float4 a = s[0], b = s[1];
    uint4 v;
    v.x = pkbf2(a.x, a.y); v.y = pkbf2(a.z, a.w);
    v.z = pkbf2(b.x, b.y); v.w = pkbf2(b.z, b.w);
    reinterpret_cast<uint4*>(pb)[idx] = v;
}

// ================= kernel A: MFMA + online row stats + S -> global =========
__global__ __launch_bounds__(NTHR) void vq_mainA(const float* __restrict__ latents,
                                                 const float* __restrict__ protos,
                                                 const float* __restrict__ gumbel,
                                                 float* __restrict__ ws,
                                                 float* __restrict__ out) {
    __shared__ __align__(16) unsigned char sm[LA_TOT];
    const int t = threadIdx.x;
    const int lane = t & 63;
    const int w = t >> 6;
    const int rb = blockIdx.x;
    const int n0 = rb * BM;
    const int l15 = lane & 15;
    const int l4 = lane >> 4;
    const float* np2 = ws;
    const uint4* pb = reinterpret_cast<const uint4*>((char*)ws + PB_OFF);
    uint2* Sb = reinterpret_cast<uint2*>((char*)ws + SBUF_OFF);
    float* lzb = reinterpret_cast<float*>((char*)ws + LZ_OFF);

    // stage X: 16 rows x 256 f32 -> bf16 LDS (swizzled)
    {
        int row = t >> 5, g = t & 31;
        const float4* src = reinterpret_cast<const float4*>(
            latents + (size_t)(n0 + row) * DD + g * 8);
        float4 a = src[0], b = src[1];
        uint4 v; v.x = pkbf2(a.x, a.y); v.y = pkbf2(a.z, a.w);
        v.z = pkbf2(b.x, b.y); v.w = pkbf2(b.z, b.w);
        *reinterpret_cast<uint4*>(sm + LXS + row * 512 + ((g ^ (row & 7)) << 4)) = v;
    }

    const int pr = w * 16 + l15;
    const int cwbase = w * 16 + l4 * 4;
    float z = 0.f, m = -3.4e38f; int mi = 0;

    for (int c = 0; c < NCHUNK; ++c) {
        __syncthreads();          // Ps readers of prev chunk done (covers Xs 1st iter)
#pragma unroll
        for (int i = 0; i < 8; ++i) {
            int G = t + NTHR * i;
            int p = G >> 5, g = G & 31;
            *reinterpret_cast<uint4*>(sm + LPS + p * 512 + ((g ^ (p & 7)) << 4)) =
                pb[(size_t)(c * CHUNK + p) * 32 + g];
        }
        __syncthreads();

        const int pg0 = c * CHUNK + cwbase;
        float4 q4 = *reinterpret_cast<const float4*>(np2 + pg0);
        float4 g4 = *reinterpret_cast<const float4*>(gumbel + (size_t)(n0 + l15) * KK + pg0);

        f32x4 acc = {0.f, 0.f, 0.f, 0.f};
#pragma unroll
        for (int ks = 0; ks < 8; ++ks) {
            int gi = ks * 4 + l4;
            bf16x8 af = *reinterpret_cast<bf16x8*>(sm + LPS + pr * 512 + ((gi ^ (pr & 7)) << 4));
            bf16x8 b0 = *reinterpret_cast<bf16x8*>(sm + LXS + l15 * 512 + ((gi ^ (l15 & 7)) << 4));
            acc = __builtin_amdgcn_mfma_f32_16x16x32_bf16(af, b0, acc, 0, 0, 0);
        }
        float s0 = fmaf(2.f, acc.x, -q4.x) + g4.x;
        float s1 = fmaf(2.f, acc.y, -q4.y) + g4.y;
        float s2 = fmaf(2.f, acc.z, -q4.z) + g4.z;
        float s3 = fmaf(2.f, acc.w, -q4.w) + g4.w;
        z += __expf(s0) + __expf(s1) + __expf(s2) + __expf(s3);
        if (s0 > m) { m = s0; mi = pg0; }
        if (s1 > m) { m = s1; mi = pg0 + 1; }
        if (s2 > m) { m = s2; mi = pg0 + 2; }
        if (s3 > m) { m = s3; mi = pg0 + 3; }
        uint2 pk;
        pk.x = pkbf2(s0, s1);
        pk.y = pkbf2(s2, s3);
        Sb[((size_t)rb * NCHUNK + c) * 512 + t] = pk;   // 512B contiguous per wave
    }

    // row stats: reduce over l4 (lane bits 4,5)
#pragma unroll
    for (int off = 16; off <= 32; off <<= 1) {
        float om = __shfl_xor(m, off); int oi = __shfl_xor(mi, off);
        if (om > m || (om == m && oi < mi)) { m = om; mi = oi; }
        z += __shfl_xor(z, off);
    }
    if (lane < 16) {
        *reinterpret_cast<float*>(sm + ASC_MAXP + (l15 * 8 + w) * 8) = m;
        *reinterpret_cast<int*>(sm + ASC_MAXP + (l15 * 8 + w) * 8 + 4) = mi;
        *reinterpret_cast<float*>(sm + ASC_ZP + (l15 * 8 + w) * 4) = z;
    }
    __syncthreads();
    if (t < 16) {
        float mm = -3.4e38f; int mmi = 0; float Z = 0.f;
#pragma unroll
        for (int j = 0; j < 8; ++j) {
            float om = *reinterpret_cast<float*>(sm + ASC_MAXP + (t * 8 + j) * 8);
            int oi = *reinterpret_cast<int*>(sm + ASC_MAXP + (t * 8 + j) * 8 + 4);
            if (om > mm || (om == mm && oi < mmi)) { mm = om; mmi = oi; }
            Z += *reinterpret_cast<float*>(sm + ASC_ZP + (t * 8 + j) * 4);
        }
        lzb[n0 + t] = __logf(Z);
        *reinterpret_cast<int*>(sm + ASC_MI + t * 4) = mmi;
    }
    __syncthreads();

    // quantized = protos[argmax], 32 thr/row
    {
        int row = t >> 5, v = t & 31;
        int idx = *reinterpret_cast<int*>(sm + ASC_MI + row * 4);
        const float4* src = reinterpret_cast<const float4*>(protos + (size_t)idx * DD + v * 8);
        float4* dst = reinterpret_cast<float4*>(out + (size_t)(n0 + row) * DD + v * 8);
        dst[0] = src[0];
        dst[1] = src[1];
    }
}

// ================= kernel B: column sums from Sbuf ==========================
__global__ __launch_bounds__(NTHR) void vq_colsum(float* __restrict__ ws) {
    const int t = threadIdx.x;
    const int l15 = t & 15;
    const int c = blockIdx.x & 7;          // chunk
    const int rg = blockIdx.x >> 3;        // row-group: 64 row-blocks
    const uint2* Sb = reinterpret_cast<const uint2*>((char*)ws + SBUF_OFF);
    const float* lzb = reinterpret_cast<const float*>((char*)ws + LZ_OFF);
    float* colsum_y = ws + KK;
    float* colsum_lp = ws + 2 * KK;

    float sy0 = 0.f, sy1 = 0.f, sy2 = 0.f, sy3 = 0.f;
    float sl0 = 0.f, sl1 = 0.f, sl2 = 0.f, sl3 = 0.f;
    for (int i = 0; i < NRB / 32; ++i) {   // 64 row-blocks
        int rb = rg * (NRB / 32) + i;
        uint2 v = Sb[((size_t)rb * NCHUNK + c) * 512 + t];
        float lz = lzb[rb * BM + l15];
        float a0 = ubf(v.x & 0xffffu) - lz, a1 = ubf(v.x >> 16) - lz;
        float a2 = ubf(v.y & 0xffffu) - lz, a3 = ubf(v.y >> 16) - lz;
        sy0 += __expf(a0); sy1 += __expf(a1); sy2 += __expf(a2); sy3 += __expf(a3);
        sl0 += a0; sl1 += a1; sl2 += a2; sl3 += a3;
    }
#pragma unroll
    for (int off = 1; off < 16; off <<= 1) {
        sy0 += __shfl_xor(sy0, off); sy1 += __shfl_xor(sy1, off);
        sy2 += __shfl_xor(sy2, off); sy3 += __shfl_xor(sy3, off);
        sl0 += __shfl_xor(sl0, off); sl1 += __shfl_xor(sl1, off);
        sl2 += __shfl_xor(sl2, off); sl3 += __shfl_xor(sl3, off);
    }
    if (l15 == 0) {
        int w = t >> 6, l4 = (t & 63) >> 4;
        int cb = c * CHUNK + w * 16 + l4 * 4;
        atomicAdd(&colsum_y[cb],     sy0); atomicAdd(&colsum_y[cb + 1], sy1);
        atomicAdd(&colsum_y[cb + 2], sy2); atomicAdd(&colsum_y[cb + 3], sy3);
        atomicAdd(&colsum_lp[cb],     sl0); atomicAdd(&colsum_lp[cb + 1], sl1);
        atomicAdd(&colsum_lp[cb + 2], sl2); atomicAdd(&colsum_lp[cb + 3], sl3);
    }
}

// ================= round-9 fallback main kernel =============================
template<bool PRE>
__global__ __launch_bounds__(NTHR) void vq_mainT(const float* __restrict__ latents,
                                                 const float* __restrict__ protos,
                                                 const float* __restrict__ gumbel,
                                                 float* __restrict__ ws,
                                                 float* __restrict__ out) {
    __shared__ __align__(16) unsigned char sm[PRE ? LTOT_PRE : LTOT_NPRE];
    const int t = threadIdx.x;
    const int lane = t & 63;
    const int w = t >> 6;
    const int n0 = blockIdx.x * BM;
    const int l15 = lane & 15;
    const int l4 = lane >> 4;
    const float* np2 = ws;
    float* colsum_y = ws + KK;
    float* colsum_lp = ws + 2 * KK;
    const uint4* pb = reinterpret_cast<const uint4*>((char*)ws + PB_OFF);

    {
        int row = t >> 5, g = t & 31;
        const float4* src = reinterpret_cast<const float4*>(
            latents + (size_t)(n0 + row) * DD + g * 8);
        float4 a = src[0], b = src[1];
        uint4 v; v.x = pkbf2(a.x, a.y); v.y = pkbf2(a.z, a.w);
        v.z = pkbf2(b.x, b.y); v.w = pkbf2(b.z, b.w);
        *reinterpret_cast<uint4*>(sm + LXS + row * 512 + ((g ^ (row & 7)) << 4)) = v;
    }
    __syncthreads();

    const int pr = w * 16 + l15;
    const int cwbase = w * 16 + l4 * 4;

    for (int c = 0; c < NCHUNK; ++c) {
        if (!PRE) {
            __syncthreads();
#pragma unroll
            for (int i = 0; i < 8; ++i) {
                int G = t + NTHR * i;
                int p = G >> 5, g = G & 31;
                const float4* src = reinterpret_cast<const float4*>(
                    protos + (size_t)(c * CHUNK + p) * DD + g * 8);
                float4 a = src[0], b = src[1];
                uint4 v; v.x = pkbf2(a.x, a.y); v.y = pkbf2(a.z, a.w);
                v.z = pkbf2(b.x, b.y); v.w = pkbf2(b.z, b.w);
                *reinterpret_cast<uint4*>(sm + FLPS + p * 512 + ((g ^ (p & 7)) << 4)) = v;
            }
            __syncthreads();
        }
        const int pg0 = c * CHUNK + cwbase;
        float4 q4 = *reinterpret_cast<const float4*>(np2 + pg0);
        float4 g4 = *reinterpret_cast<const float4*>(gumbel + (size_t)(n0 + l15) * KK + pg0);

        f32x4 acc = {0.f, 0.f, 0.f, 0.f};
        if (PRE) {
            const uint4* afp = pb + (size_t)(c * CHUNK + pr) * 32;
#pragma unroll
            for (int ks = 0; ks < 8; ++ks) {
                int gi = ks * 4 + l4;
                bf16x8 af = __builtin_bit_cast(bf16x8, afp[gi]);
                bf16x8 b0 = *reinterpret_cast<bf16x8*>(
                    sm + LXS + l15 * 512 + ((gi ^ (l15 & 7)) << 4));
                acc = __builtin_amdgcn_mfma_f32_16x16x32_bf16(af, b0, acc, 0, 0, 0);
            }
        } else {
#pragma unroll
            for (int ks = 0; ks < 8; ++ks) {
                int gi = ks * 4 + l4;
                bf16x8 af = *reinterpret_cast<bf16x8*>(
                    sm + FLPS + pr * 512 + ((gi ^ (pr & 7)) << 4));
                bf16x8 b0 = *reinterpret_cast<bf16x8*>(
                    sm + LXS + l15 * 512 + ((gi ^ (l15 & 7)) << 4));
                acc = __builtin_amdgcn_mfma_f32_16x16x32_bf16(af, b0, acc, 0, 0, 0);
            }
        }
        {
            const int Gs = pg0 >> 2;
            uint2 pk;
            pk.x = pkbf2(fmaf(2.f, acc.x, -q4.x) + g4.x, fmaf(2.f, acc.y, -q4.y) + g4.y);
            pk.y = pkbf2(fmaf(2.f, acc.z, -q4.z) + g4.z, fmaf(2.f, acc.w, -q4.w) + g4.w);
            *reinterpret_cast<uint2*>(sm + LSS + l15 * 2048 + ((Gs ^ ((l15 & 7) << 1)) << 3)) = pk;
        }
    }
    __syncthreads();

    {
        int row = t >> 5, v = t & 31;
        int sw = (row & 7) << 1;
        uint2 d[8];
#pragma unroll
        for (int j = 0; j < 8; ++j) {
            int G = v + 32 * j;
            d[j] = *reinterpret_cast<uint2*>(sm + LSS + row * 2048 + ((G ^ sw) << 3));
        }
        float m = -3.4e38f; int mi = 0;
#pragma unroll
        for (int j = 0; j < 8; ++j) {
            int c0 = (v + 32 * j) * 4;
            float f0 = ubf(d[j].x & 0xffffu), f1 = ubf(d[j].x >> 16);
            float f2 = ubf(d[j].y & 0xffffu), f3 = ubf(d[j].y >> 16);
            if (f0 > m) { m = f0; mi = c0; }
            if (f1 > m) { m = f1; mi = c0 + 1; }
            if (f2 > m) { m = f2; mi = c0 + 2; }
            if (f3 > m) { m = f3; mi = c0 + 3; }
        }
#pragma unroll
        for (int off = 1; off < 32; off <<= 1) {
            float om = __shfl_xor(m, off);
            int oi = __shfl_xor(mi, off);
            if (om > m || (om == m && oi < mi)) { m = om; mi = oi; }
        }
        float se = 0.f;
#pragma unroll
        for (int j = 0; j < 8; ++j) {
            se += __expf(ubf(d[j].x & 0xffffu) - m);
            se += __expf(ubf(d[j].x >> 16) - m);
            se += __expf(ubf(d[j].y & 0xffffu) - m);
            se += __expf(ubf(d[j].y >> 16) - m);
        }
#pragma unroll
        for (int off = 1; off < 32; off <<= 1) se += __shfl_xor(se, off);
        if (v == 0) {
            *reinterpret_cast<float*>(sm + LRM + row * 4) = m + __logf(se);
            *reinterpret_cast<int*>(sm + LRI + row * 4) = mi;
        }
    }
    __syncthreads();

#pragma unroll
    for (int h = 0; h < 2; ++h) {
        int col = t + h * NTHR;
        int G = col >> 2;
        int e2 = (col & 3) << 1;
        float sy = 0.f, slp = 0.f;
#pragma unroll 8
        for (int r = 0; r < BM; ++r) {
            uint32_t hv = *reinterpret_cast<uint16_t*>(
                sm + LSS + r * 2048 + ((G ^ ((r & 7) << 1)) << 3) + e2);
            float lz = *reinterpret_cast<float*>(sm + LRM + r * 4);
            float lp = ubf(hv) - lz;
            slp += lp;
            sy += __expf(lp);
        }
        atomicAdd(&colsum_y[col], sy);
        atomicAdd(&colsum_lp[col], slp);
    }

    {
        int row = t >> 5, v = t & 31;
        int idx = *reinterpret_cast<int*>(sm + LRI + row * 4);
        const float4* src = reinterpret_cast<const float4*>(protos + (size_t)idx * DD + v * 8);
        float4* dst = reinterpret_cast<float4*>(out + (size_t)(n0 + row) * DD + v * 8);
        dst[0] = src[0];
        dst[1] = src[1];
    }
}

__global__ void vq_final(const float* __restrict__ ws,
                         float* __restrict__ out, int out_size) {
    __shared__ float part[4];
    int t = threadIdx.x;  // 1 block x 256
    const float invN = 1.0f / (float)NN;
    float a = 0.f;
    for (int j = 0; j < 4; ++j) {
        int k = t + j * 256;
        float prior = fmaf(ws[KK + k], invN, 1e-6f);
        float Lk = ws[2 * KK + k] * invN;
        a += prior * (1.001f * __logf(prior) - Lk);
    }
#pragma unroll
    for (int off = 32; off >= 1; off >>= 1) a += __shfl_xor(a, off);
    if ((t & 63) == 0) part[t >> 6] = a;
    __syncthreads();
    if (t == 0) {
        out[out_size - 1] = part[0] + part[1] + part[2] + part[3];
    }
}

extern "C" void kernel_launch(void* const* d_in, const int* in_sizes, int n_in,
                              void* d_out, int out_size, void* d_ws, size_t ws_size,
                              hipStream_t stream) {
    (void)in_sizes; (void)n_in;
    const float* latents = (const float*)d_in[0];
    const float* protos  = (const float*)d_in[1];
    const float* gumbel  = (const float*)d_in[2];
    float* out           = (float*)d_out;
    float* ws            = (float*)d_ws;

    vq_init<<<dim3(4), dim3(256), 0, stream>>>(protos, ws);
    if (ws_size >= WS_FULL) {
        vq_cvt<<<dim3(KK * DD / 2048), dim3(256), 0, stream>>>(
            protos, (uint32_t*)((char*)d_ws + PB_OFF));
        vq_mainA<<<dim3(NRB), dim3(NTHR), 0, stream>>>(
            latents, protos, gumbel, ws, out);
        vq_colsum<<<dim3(NCHUNK * 32), dim3(NTHR), 0, stream>>>(ws);
    } else if (ws_size >= WS_PRE) {
        vq_cvt<<<dim3(KK * DD / 2048), dim3(256), 0, stream>>>(
            protos, (uint32_t*)((char*)d_ws + PB_OFF));
        vq_mainT<true><<<dim3(NRB), dim3(NTHR), 0, stream>>>(
            latents, protos, gumbel, ws, out);
    } else {
        vq_mainT<false><<<dim3(NRB), dim3(NTHR), 0, stream>>>(
            latents, protos, gumbel, ws, out);
    }
    vq_final<<<dim3(1), dim3(256), 0, stream>>>(ws, out, out_size);
}